// Round 1
// baseline (146.061 us; speedup 1.0000x reference)
//
#include <hip/hip_runtime.h>

// DmvCell RNN scan: per (b,d) chain over T steps of
//   count+=1; s+=x; mx=max(mx,x); mean=s/count;
//   sn+=(x-prev_mean)*(x-mean); var=sn/count; out=[mean,var,mx]
// B=32, T=2048, D=512. Memory-bound: 128MB in + 384MB out.
//
// Parallelization: block = (b, 64-wide d-group) -> 256 blocks x 256 threads.
// 4 waves split each 256-step super-tile into 64-step chunks; Welford
// chunk aggregates are merged (parallel-variance formula) to give each
// wave its exact carry; pass 2 rescans the chunk from LDS writing outputs.
// Input is read from HBM exactly once (reg-staged prefetch of next tile
// overlaps compute). Each wave stages and reads only its own LDS rows ->
// single __syncthreads per tile (aggs exchange), aggs double-buffered.

#define BB 32
#define TT 2048
#define DD 512
#define TILE_T 256
#define CHUNK 64
#define NTILES (TT / TILE_T)  // 8
#define NWAVES 4
#define DGRP 64

__device__ __forceinline__ float fast_rcp(float x) {
#if __has_builtin(__builtin_amdgcn_rcpf)
    return __builtin_amdgcn_rcpf(x);
#else
    return 1.0f / x;
#endif
}

__launch_bounds__(256, 1)
__global__ void dmv_scan_kernel(const float* __restrict__ x,
                                float* __restrict__ out) {
    __shared__ float tile[TILE_T * DGRP];        // 64 KB
    __shared__ float aggs[2][NWAVES][3][DGRP];   // 6 KB: [buf][wave][{s,m2,mx}][lane]

    const int tid = threadIdx.x;
    const int w   = tid >> 6;   // wave 0..3 = T-chunk within tile
    const int l   = tid & 63;   // lane = d within group
    const int b   = blockIdx.x >> 3;
    const int d0  = (blockIdx.x & 7) * DGRP;

    const float* xbase = x   + ((size_t)b * TT) * DD + d0;        // row stride DD
    float*       obase = out + ((size_t)b * TT) * (3 * DD) + d0;  // row stride 3*DD

    // staging map: lane l loads rows w*64 + r*4 + (l>>4), cols (l&15)*4..+3
    const int srow = (l >> 4);
    const int scol = (l & 15) * 4;

    float4 regs[16];

    // prologue: load tile 0 (own chunk rows)
    #pragma unroll
    for (int r = 0; r < 16; ++r) {
        int t = w * CHUNK + r * 4 + srow;
        regs[r] = *(const float4*)(xbase + (size_t)t * DD + scol);
    }

    // block carry (all waves maintain identical copies). count is uniform.
    float c_n = 0.f, c_s = 0.f, c_m2 = 0.f, c_mx = 0.f;

    for (int s = 0; s < NTILES; ++s) {
        // write current tile (own rows) to LDS
        #pragma unroll
        for (int r = 0; r < 16; ++r) {
            int row = w * CHUNK + r * 4 + srow;
            *(float4*)(&tile[row * DGRP + scol]) = regs[r];
        }
        // prefetch next tile into regs (overlaps pass 1; WAR on regs is
        // resolved at ds_write issue)
        if (s + 1 < NTILES) {
            const float* xt = xbase + (size_t)(s + 1) * TILE_T * DD;
            #pragma unroll
            for (int r = 0; r < 16; ++r) {
                int t = w * CHUNK + r * 4 + srow;
                regs[r] = *(const float4*)(xt + (size_t)t * DD + scol);
            }
        }

        // ---- pass 1: chunk-local Welford (zero start; max clamps at 0
        //      exactly like the reference's zero-init max state) ----
        const float* tbase = &tile[(w * CHUNK) * DGRP + l];
        float p_s = 0.f, p_m2 = 0.f, p_mx = 0.f, p_mean = 0.f, cnt = 0.f;
        #pragma unroll 16
        for (int k = 0; k < CHUNK; ++k) {
            float xv = tbase[k * DGRP];
            cnt += 1.f;
            p_s += xv;
            p_mx = fmaxf(p_mx, xv);
            float inv = fast_rcp(cnt);
            float nm  = p_s * inv;
            p_m2 += (xv - p_mean) * (xv - nm);
            p_mean = nm;
        }
        const int ab = s & 1;
        aggs[ab][w][0][l] = p_s;
        aggs[ab][w][1][l] = p_m2;
        aggs[ab][w][2][l] = p_mx;
        __syncthreads();

        // ---- merge: fold carry with all 4 chunk aggregates; capture my
        //      start state just before folding my own chunk ----
        float st_n = c_n, st_s = c_s, st_m2 = c_m2, st_mx = c_mx;
        float my_n = 0.f, my_s = 0.f, my_m2 = 0.f, my_mx = 0.f;
        #pragma unroll
        for (int j = 0; j < NWAVES; ++j) {
            if (j == w) { my_n = st_n; my_s = st_s; my_m2 = st_m2; my_mx = st_mx; }
            float bs  = aggs[ab][j][0][l];
            float bm2 = aggs[ab][j][1][l];
            float bmx = aggs[ab][j][2][l];
            if (st_n == 0.f) {  // uniform branch (count is uniform)
                st_n = 64.f; st_s = bs; st_m2 = bm2; st_mx = bmx;
            } else {
                float n  = st_n + 64.f;
                float da = bs * (1.0f / 64.0f) - st_s / st_n;
                st_m2 = st_m2 + bm2 + da * da * (st_n * 64.f / n);
                st_s += bs;
                st_mx = fmaxf(st_mx, bmx);
                st_n  = n;
            }
        }
        c_n = st_n; c_s = st_s; c_m2 = st_m2; c_mx = st_mx;

        // ---- pass 2: exact sequential scan of my chunk from merged carry ----
        float cnt2 = my_n;
        float rs = my_s, rm2 = my_m2, rmx = my_mx;
        float rmean = (cnt2 > 0.f) ? rs / cnt2 : 0.f;
        float* ob = obase + (size_t)(s * TILE_T + w * CHUNK) * (3 * DD) + l;
        #pragma unroll 8
        for (int k = 0; k < CHUNK; ++k) {
            float xv = tbase[k * DGRP];
            cnt2 += 1.f;
            float inv = fast_rcp(cnt2);
            rs += xv;
            rmx = fmaxf(rmx, xv);
            float nm = rs * inv;
            rm2 += (xv - rmean) * (xv - nm);
            rmean = nm;
            float var = rm2 * inv;
            float* orow = ob + (size_t)k * (3 * DD);
            orow[0]      = nm;
            orow[DD]     = var;
            orow[2 * DD] = rmx;
        }
        // no second barrier needed: aggs are double-buffered, and tile rows
        // are wave-private (staged and read only by their owning wave).
    }
}

extern "C" void kernel_launch(void* const* d_in, const int* in_sizes, int n_in,
                              void* d_out, int out_size, void* d_ws, size_t ws_size,
                              hipStream_t stream) {
    (void)in_sizes; (void)n_in; (void)d_ws; (void)ws_size; (void)out_size;
    const float* x = (const float*)d_in[0];
    float* out = (float*)d_out;
    dim3 grid(BB * (DD / DGRP));  // 256 blocks
    dim3 block(256);
    dmv_scan_kernel<<<grid, block, 0, stream>>>(x, out);
}

// Round 2
// 139.433 us; speedup vs baseline: 1.0475x; 1.0475x over previous
//
#include <hip/hip_runtime.h>

// DmvCell RNN scan, B=32, T=2048, D=512. out[b][t] = [mean|var|max] (3*D).
// Memory-bound: 128 MB in + 384 MB out (compulsory).
//
// R2 design: barrier-free streaming. 256 blocks (b x 8 d-groups) x 1024
// threads (16 waves). Wave w owns T-chunk [w*128, w*128+128) of the block's
// 64-wide d-group.
//  phase 1: stream chunk once computing (sum, sumsq, max) -> chunk agg in LDS
//  ONE __syncthreads
//  prefix-fold aggregates of chunks 0..w-1 (parallel-variance merge) -> carry
//  phase 2: exact sequential rescan of own chunk from carry, streaming
//           3 coalesced dword stores/step, no barriers -> store pipe streams.
// Phase-2 input re-reads hit L2/L3 (input 128 MB < 256 MB L3).

#define BB 32
#define TT 2048
#define DD 512
#define DGRP 64
#define NW 16
#define CHUNK (TT / NW)  // 128

__device__ __forceinline__ float fast_rcp(float x) {
#if __has_builtin(__builtin_amdgcn_rcpf)
    return __builtin_amdgcn_rcpf(x);
#else
    return 1.0f / x;
#endif
}

__launch_bounds__(1024, 1)
__global__ void dmv_scan_kernel(const float* __restrict__ x,
                                float* __restrict__ out) {
    __shared__ float aggS[NW][DGRP];
    __shared__ float aggM2[NW][DGRP];
    __shared__ float aggMX[NW][DGRP];

    const int tid = threadIdx.x;
    const int w   = tid >> 6;   // wave = T-chunk index
    const int l   = tid & 63;   // lane = d within group
    const int b   = blockIdx.x >> 3;
    const int d0  = (blockIdx.x & 7) * DGRP;

    const float* xp = x   + ((size_t)b * TT) * DD + d0 + l
                          + (size_t)(w * CHUNK) * DD;
    float*       op = out + ((size_t)b * TT) * (3 * DD) + d0 + l
                          + (size_t)(w * CHUNK) * (3 * DD);

    // ---- phase 1: chunk aggregate (wave NW-1's agg is never consumed) ----
    if (w < NW - 1) {
        float s = 0.f, ss = 0.f, mx = 0.f;
        #pragma unroll 8
        for (int k = 0; k < CHUNK; ++k) {
            float xv = xp[(size_t)k * DD];
            s  += xv;
            ss  = fmaf(xv, xv, ss);
            mx  = fmaxf(mx, xv);
        }
        aggS[w][l]  = s;
        aggM2[w][l] = ss - s * s * (1.0f / CHUNK);
        aggMX[w][l] = mx;
    }
    __syncthreads();

    // ---- prefix-fold chunks 0..w-1 (w uniform per wave; no divergence) ----
    float c_n = 0.f, c_s = 0.f, c_m2 = 0.f, c_mx = 0.f;
    for (int j = 0; j < w; ++j) {
        float bs = aggS[j][l], bm2 = aggM2[j][l], bmx = aggMX[j][l];
        if (j == 0) {
            c_n = (float)CHUNK; c_s = bs; c_m2 = bm2; c_mx = bmx;
        } else {
            float n  = c_n + (float)CHUNK;
            float da = bs * (1.0f / CHUNK) - c_s / c_n;
            c_m2 = c_m2 + bm2 + da * da * (c_n * (float)CHUNK / n);
            c_s += bs;
            c_mx = fmaxf(c_mx, bmx);
            c_n  = n;
        }
    }

    // ---- phase 2: exact sequential scan of own chunk from merged carry ----
    float cnt   = c_n;
    float rs    = c_s, rm2 = c_m2, rmx = c_mx;
    float rmean = (w > 0) ? rs / cnt : 0.f;
    #pragma unroll 8
    for (int k = 0; k < CHUNK; ++k) {
        float xv = xp[(size_t)k * DD];
        cnt += 1.f;
        float inv = fast_rcp(cnt);
        rs  += xv;
        rmx  = fmaxf(rmx, xv);
        float nm = rs * inv;
        rm2 += (xv - rmean) * (xv - nm);
        rmean = nm;
        float var = rm2 * inv;
        float* orow = op + (size_t)k * (3 * DD);
        orow[0]      = nm;
        orow[DD]     = var;
        orow[2 * DD] = rmx;
    }
}

extern "C" void kernel_launch(void* const* d_in, const int* in_sizes, int n_in,
                              void* d_out, int out_size, void* d_ws, size_t ws_size,
                              hipStream_t stream) {
    (void)in_sizes; (void)n_in; (void)d_ws; (void)ws_size; (void)out_size;
    const float* x = (const float*)d_in[0];
    float* out = (float*)d_out;
    dim3 grid(BB * (DD / DGRP));  // 256 blocks
    dim3 block(1024);             // 16 waves
    dmv_scan_kernel<<<grid, block, 0, stream>>>(x, out);
}